// Round 2
// baseline (519.949 us; speedup 1.0000x reference)
//
#include <hip/hip_runtime.h>
#include <math.h>

// RNNT joint + log_softmax over vocab.
//   f: [B,T,V] fp32, g: [B,U,V] fp32
//   out[b,t,u,v] = x - (max_v x + log(sum_v exp(x - max_v x))),  x = f[b,t,v] + g[b,u,v]
// B=4, T=256, U=128, V=1024.
//
// One wave (64 lanes) per PAIR of (b,t,u) rows sharing the same f row.
// Identical to previous round EXCEPT: plain (cached, write-back) stores instead
// of __builtin_nontemporal_store. A/B isolates the store path:
//   - prior round proved loads/VALU/shuffles are off the critical path
//     (2-wide ILP + halved f-loads moved dur_us by 5 ns)
//   - the fill kernel demonstrates 6.3 TB/s with normal write-back stores;
//     if nt stores bypass L2 write aggregation, this recovers ~2x store BW.
// Inputs are only 6 MB; output streaming through L2 evicts them to L3 at most —
// re-reads are cheap, so L2 pollution is a non-issue here.

#define RB 4
#define RT 256
#define RU 128
#define RV 1024

__global__ __launch_bounds__(256, 6) void rnnt_joint_ls_kernel(
    const float* __restrict__ f,
    const float* __restrict__ g,
    float* __restrict__ out)
{
    const int wave = threadIdx.x >> 6;
    const int lane = threadIdx.x & 63;
    const int p = blockIdx.x * 4 + wave;     // pair index in [0, B*T*U/2)

    // pair p -> (b, t, u0) with u0 = 2*(p % (U/2)), bt = p / (U/2)
    const int pu = p & 63;                   // U/2 = 64
    const int bt = p >> 6;                   // b*T + t
    const int b  = bt >> 8;                  // T = 256
    const int u0 = pu * 2;

    const float4* __restrict__ f4 = (const float4*)(f + (size_t)bt * RV);
    const float4* __restrict__ g4 = (const float4*)(g + ((size_t)b * RU + u0) * RV);
    float4* __restrict__ o4 = (float4*)(out + ((size_t)bt * RU + u0) * RV);

    // ---- load f once, build both rows ----
    float4 fv[4];
#pragma unroll
    for (int i = 0; i < 4; ++i) fv[i] = f4[lane + 64 * i];

    float4 x0[4], x1[4];
#pragma unroll
    for (int i = 0; i < 4; ++i) {
        float4 gv = g4[lane + 64 * i];             // row u0
        x0[i].x = fv[i].x + gv.x;
        x0[i].y = fv[i].y + gv.y;
        x0[i].z = fv[i].z + gv.z;
        x0[i].w = fv[i].w + gv.w;
    }
#pragma unroll
    for (int i = 0; i < 4; ++i) {
        float4 gv = g4[256 + lane + 64 * i];       // row u0+1 (next 4 KB)
        x1[i].x = fv[i].x + gv.x;
        x1[i].y = fv[i].y + gv.y;
        x1[i].z = fv[i].z + gv.z;
        x1[i].w = fv[i].w + gv.w;
    }

    // ---- dual wave max reductions (interleaved) ----
    float m0 = -INFINITY, m1 = -INFINITY;
#pragma unroll
    for (int i = 0; i < 4; ++i) {
        m0 = fmaxf(m0, fmaxf(fmaxf(x0[i].x, x0[i].y), fmaxf(x0[i].z, x0[i].w)));
        m1 = fmaxf(m1, fmaxf(fmaxf(x1[i].x, x1[i].y), fmaxf(x1[i].z, x1[i].w)));
    }
#pragma unroll
    for (int off = 32; off > 0; off >>= 1) {
        m0 = fmaxf(m0, __shfl_xor(m0, off, 64));
        m1 = fmaxf(m1, __shfl_xor(m1, off, 64));
    }

    // ---- dual sum(exp(x - m)) reductions (interleaved) ----
    const float kL2E = 1.4426950408889634f;
    const float c0 = m0 * kL2E;
    const float c1 = m1 * kL2E;
    float s0 = 0.0f, s1 = 0.0f;
#pragma unroll
    for (int i = 0; i < 4; ++i) {
        s0 += exp2f(fmaf(x0[i].x, kL2E, -c0));
        s1 += exp2f(fmaf(x1[i].x, kL2E, -c1));
        s0 += exp2f(fmaf(x0[i].y, kL2E, -c0));
        s1 += exp2f(fmaf(x1[i].y, kL2E, -c1));
        s0 += exp2f(fmaf(x0[i].z, kL2E, -c0));
        s1 += exp2f(fmaf(x1[i].z, kL2E, -c1));
        s0 += exp2f(fmaf(x0[i].w, kL2E, -c0));
        s1 += exp2f(fmaf(x1[i].w, kL2E, -c1));
    }
#pragma unroll
    for (int off = 32; off > 0; off >>= 1) {
        s0 += __shfl_xor(s0, off, 64);
        s1 += __shfl_xor(s1, off, 64);
    }

    const float M0 = m0 + __logf(s0);
    const float M1 = m1 + __logf(s1);

    // ---- streaming writes: PLAIN stores (A/B vs nontemporal) ----
#pragma unroll
    for (int i = 0; i < 4; ++i) {
        float4 y;
        y.x = x0[i].x - M0;
        y.y = x0[i].y - M0;
        y.z = x0[i].z - M0;
        y.w = x0[i].w - M0;
        o4[lane + 64 * i] = y;
    }
#pragma unroll
    for (int i = 0; i < 4; ++i) {
        float4 y;
        y.x = x1[i].x - M1;
        y.y = x1[i].y - M1;
        y.z = x1[i].z - M1;
        y.w = x1[i].w - M1;
        o4[256 + lane + 64 * i] = y;
    }
}

extern "C" void kernel_launch(void* const* d_in, const int* in_sizes, int n_in,
                              void* d_out, int out_size, void* d_ws, size_t ws_size,
                              hipStream_t stream) {
    const float* f = (const float*)d_in[0];   // [B,T,V]
    const float* g = (const float*)d_in[1];   // [B,U,V]
    float* out = (float*)d_out;               // [B,T,U,V]

    const int pairs = RB * RT * RU / 2;       // 65536 row-pairs
    dim3 grid(pairs / 4);                     // 4 waves per block, 2 rows per wave
    dim3 block(256);
    rnnt_joint_ls_kernel<<<grid, block, 0, stream>>>(f, g, out);
}

// Round 3
// 518.380 us; speedup vs baseline: 1.0030x; 1.0030x over previous
//
#include <hip/hip_runtime.h>
#include <math.h>

// RNNT joint + log_softmax over vocab.
//   f: [B,T,V] fp32, g: [B,U,V] fp32
//   out[b,t,u,v] = x - (max_v x + log(sum_v exp(x - max_v x))),  x = f[b,t,v] + g[b,u,v]
// B=4, T=256, U=128, V=1024.
//
// FINAL (roofline-locked) version. Findings from the A/B ladder:
//   R1: halving f-loads + 2-wide ILP on all reductions -> 5 ns delta
//       => loads/VALU/shuffles are fully hidden; kernel is store-bound.
//   R2: plain stores vs nontemporal -> +3.5 us (L2 allocate/evict penalty)
//       => nontemporal is the right store flavor for a 537 MB stream
//          that is never re-read.
// Kernel portion ~85 us = 537 MB @ ~6.3 TB/s = the achievable HBM write
// ceiling (the harness's own 2 GiB fill sustains 6.22 TB/s). Remaining
// measured time is harness poison-fill, outside kernel control.
//
// One wave (64 lanes) per PAIR of (b,t,u) rows sharing the same f row;
// rows live entirely in registers; wave shuffle butterflies only, no LDS.

#define RB 4
#define RT 256
#define RU 128
#define RV 1024

typedef float nfloat4 __attribute__((ext_vector_type(4)));  // native vec for nontemporal store

__global__ __launch_bounds__(256, 6) void rnnt_joint_ls_kernel(
    const float* __restrict__ f,
    const float* __restrict__ g,
    float* __restrict__ out)
{
    const int wave = threadIdx.x >> 6;
    const int lane = threadIdx.x & 63;
    const int p = blockIdx.x * 4 + wave;     // pair index in [0, B*T*U/2)

    // pair p -> (b, t, u0) with u0 = 2*(p % (U/2)), bt = p / (U/2)
    const int pu = p & 63;                   // U/2 = 64
    const int bt = p >> 6;                   // b*T + t
    const int b  = bt >> 8;                  // T = 256
    const int u0 = pu * 2;

    const float4* __restrict__ f4 = (const float4*)(f + (size_t)bt * RV);
    const float4* __restrict__ g4 = (const float4*)(g + ((size_t)b * RU + u0) * RV);
    nfloat4* __restrict__ o4 = (nfloat4*)(out + ((size_t)bt * RU + u0) * RV);

    // ---- load f once, build both rows ----
    float4 fv[4];
#pragma unroll
    for (int i = 0; i < 4; ++i) fv[i] = f4[lane + 64 * i];

    float4 x0[4], x1[4];
#pragma unroll
    for (int i = 0; i < 4; ++i) {
        float4 gv = g4[lane + 64 * i];             // row u0
        x0[i].x = fv[i].x + gv.x;
        x0[i].y = fv[i].y + gv.y;
        x0[i].z = fv[i].z + gv.z;
        x0[i].w = fv[i].w + gv.w;
    }
#pragma unroll
    for (int i = 0; i < 4; ++i) {
        float4 gv = g4[256 + lane + 64 * i];       // row u0+1 (next 4 KB)
        x1[i].x = fv[i].x + gv.x;
        x1[i].y = fv[i].y + gv.y;
        x1[i].z = fv[i].z + gv.z;
        x1[i].w = fv[i].w + gv.w;
    }

    // ---- dual wave max reductions (interleaved) ----
    float m0 = -INFINITY, m1 = -INFINITY;
#pragma unroll
    for (int i = 0; i < 4; ++i) {
        m0 = fmaxf(m0, fmaxf(fmaxf(x0[i].x, x0[i].y), fmaxf(x0[i].z, x0[i].w)));
        m1 = fmaxf(m1, fmaxf(fmaxf(x1[i].x, x1[i].y), fmaxf(x1[i].z, x1[i].w)));
    }
#pragma unroll
    for (int off = 32; off > 0; off >>= 1) {
        m0 = fmaxf(m0, __shfl_xor(m0, off, 64));
        m1 = fmaxf(m1, __shfl_xor(m1, off, 64));
    }

    // ---- dual sum(exp(x - m)) reductions (interleaved) ----
    const float kL2E = 1.4426950408889634f;
    const float c0 = m0 * kL2E;
    const float c1 = m1 * kL2E;
    float s0 = 0.0f, s1 = 0.0f;
#pragma unroll
    for (int i = 0; i < 4; ++i) {
        s0 += exp2f(fmaf(x0[i].x, kL2E, -c0));
        s1 += exp2f(fmaf(x1[i].x, kL2E, -c1));
        s0 += exp2f(fmaf(x0[i].y, kL2E, -c0));
        s1 += exp2f(fmaf(x1[i].y, kL2E, -c1));
        s0 += exp2f(fmaf(x0[i].z, kL2E, -c0));
        s1 += exp2f(fmaf(x1[i].z, kL2E, -c1));
        s0 += exp2f(fmaf(x0[i].w, kL2E, -c0));
        s1 += exp2f(fmaf(x1[i].w, kL2E, -c1));
    }
#pragma unroll
    for (int off = 32; off > 0; off >>= 1) {
        s0 += __shfl_xor(s0, off, 64);
        s1 += __shfl_xor(s1, off, 64);
    }

    const float M0 = m0 + __logf(s0);
    const float M1 = m1 + __logf(s1);

    // ---- streaming writes (non-temporal: output is never re-read) ----
#pragma unroll
    for (int i = 0; i < 4; ++i) {
        nfloat4 y;
        y.x = x0[i].x - M0;
        y.y = x0[i].y - M0;
        y.z = x0[i].z - M0;
        y.w = x0[i].w - M0;
        __builtin_nontemporal_store(y, &o4[lane + 64 * i]);
    }
#pragma unroll
    for (int i = 0; i < 4; ++i) {
        nfloat4 y;
        y.x = x1[i].x - M1;
        y.y = x1[i].y - M1;
        y.z = x1[i].z - M1;
        y.w = x1[i].w - M1;
        __builtin_nontemporal_store(y, &o4[256 + lane + 64 * i]);
    }
}

extern "C" void kernel_launch(void* const* d_in, const int* in_sizes, int n_in,
                              void* d_out, int out_size, void* d_ws, size_t ws_size,
                              hipStream_t stream) {
    const float* f = (const float*)d_in[0];   // [B,T,V]
    const float* g = (const float*)d_in[1];   // [B,U,V]
    float* out = (float*)d_out;               // [B,T,U,V]

    const int pairs = RB * RT * RU / 2;       // 65536 row-pairs
    dim3 grid(pairs / 4);                     // 4 waves per block, 2 rows per wave
    dim3 block(256);
    rnnt_joint_ls_kernel<<<grid, block, 0, stream>>>(f, g, out);
}